// Round 1
// baseline (142.613 us; speedup 1.0000x reference)
//
#include <hip/hip_runtime.h>

// Problem constants
#define BB 256
#define NN 5
#define CC_ 640
#define HH 10
#define WW 10
#define CHW 64000            // C*H*W floats per (b,n)
#define DD 800               // 32*5*5 pooled dims
#define EPSF 1e-8f

// ---------------- Kernel 1: adaptive avg pool per (b,n) ----------------
// feats[bn*800 + d] = mean over 20 channels x 2h x 2w block.
// float2 = one (h, ow) pair since W=10, ow=w/2.
__global__ __launch_bounds__(256) void k_pool(const float* __restrict__ x,
                                              float* __restrict__ feats) {
    const int bn = blockIdx.x;  // 0..1279
    const float2* __restrict__ xp =
        reinterpret_cast<const float2*>(x + (size_t)bn * CHW);
    float* __restrict__ fp = feats + (size_t)bn * DD;
    for (int d = threadIdx.x; d < DD; d += 256) {
        const int oc  = d / 25;
        const int rem = d - oc * 25;
        const int oh  = rem / 5;
        const int ow  = rem - oh * 5;
        // float2 index: c*50 + h*5 + ow, with c = oc*20+cc, h = oh*2+hh
        int base = oc * 20 * 50 + oh * 10 + ow;
        float s = 0.f;
        #pragma unroll
        for (int cc = 0; cc < 20; ++cc) {
            float2 a = xp[base + cc * 50];
            float2 b = xp[base + cc * 50 + 5];
            s += (a.x + a.y) + (b.x + b.y);
        }
        fp[d] = s * (1.0f / 80.0f);
    }
}

// ---------------- Kernel 2: cosine sims, one wave per b ----------------
__global__ __launch_bounds__(64) void k_sim(const float* __restrict__ feats,
                                            float* __restrict__ sim) {
    const int b = blockIdx.x;
    const int lane = threadIdx.x;
    const float* __restrict__ fb = feats + (size_t)b * NN * DD;
    float dot[NN] = {0.f, 0.f, 0.f, 0.f, 0.f};
    float na2[NN] = {0.f, 0.f, 0.f, 0.f, 0.f};
    float nb2 = 0.f;
    for (int d = lane; d < DD; d += 64) {
        float f[NN];
        float p = 0.f;
        #pragma unroll
        for (int n = 0; n < NN; ++n) { f[n] = fb[n * DD + d]; p += f[n]; }
        #pragma unroll
        for (int n = 0; n < NN; ++n) {
            dot[n] += f[n] * p;
            na2[n] += f[n] * f[n];
        }
        nb2 += p * p;
    }
    #pragma unroll
    for (int off = 32; off >= 1; off >>= 1) {
        #pragma unroll
        for (int n = 0; n < NN; ++n) {
            dot[n] += __shfl_down(dot[n], off, 64);
            na2[n] += __shfl_down(na2[n], off, 64);
        }
        nb2 += __shfl_down(nb2, off, 64);
    }
    if (lane == 0) {
        const float nb = sqrtf(nb2);
        #pragma unroll
        for (int n = 0; n < NN; ++n) {
            const float denom = fmaxf(sqrtf(na2[n]) * nb, EPSF);
            sim[b * NN + n] = dot[n] / denom;
        }
    }
}

// ---------------- Kernel 3: out[b] = sum_n sim[b,n] * x[b,n] -----------
// One float4 per thread. 16000 float4 per b chunk; b is wave-uniform.
__global__ __launch_bounds__(256) void k_out(const float* __restrict__ x,
                                             const float* __restrict__ sim,
                                             float* __restrict__ out) {
    const int i = blockIdx.x * 256 + threadIdx.x;   // 0 .. BB*16000-1
    const int b = i / 16000;
    const int r = i - b * 16000;
    const float4* __restrict__ xp =
        reinterpret_cast<const float4*>(x) + (size_t)b * (NN * 16000) + r;
    const float s0 = sim[b * NN + 0];
    const float s1 = sim[b * NN + 1];
    const float s2 = sim[b * NN + 2];
    const float s3 = sim[b * NN + 3];
    const float s4 = sim[b * NN + 4];
    const float4 a0 = xp[0 * 16000];
    const float4 a1 = xp[1 * 16000];
    const float4 a2 = xp[2 * 16000];
    const float4 a3 = xp[3 * 16000];
    const float4 a4 = xp[4 * 16000];
    float4 o;
    o.x = s0 * a0.x + s1 * a1.x + s2 * a2.x + s3 * a3.x + s4 * a4.x;
    o.y = s0 * a0.y + s1 * a1.y + s2 * a2.y + s3 * a3.y + s4 * a4.y;
    o.z = s0 * a0.z + s1 * a1.z + s2 * a2.z + s3 * a3.z + s4 * a4.z;
    o.w = s0 * a0.w + s1 * a1.w + s2 * a2.w + s3 * a3.w + s4 * a4.w;
    reinterpret_cast<float4*>(out)[i] = o;
}

extern "C" void kernel_launch(void* const* d_in, const int* in_sizes, int n_in,
                              void* d_out, int out_size, void* d_ws, size_t ws_size,
                              hipStream_t stream) {
    const float* x = (const float*)d_in[0];
    float* out = (float*)d_out;
    // workspace layout: feats [B*N*800] f32, then sim [B*N] f32
    float* feats = (float*)d_ws;
    float* sim = feats + (size_t)BB * NN * DD;

    k_pool<<<BB * NN, 256, 0, stream>>>(x, feats);
    k_sim<<<BB, 64, 0, stream>>>(feats, sim);
    // BB * 16000 float4 outputs / 256 threads = 16000 blocks
    k_out<<<BB * 16000 / 256, 256, 0, stream>>>(x, sim, out);
}

// Round 2
// 141.706 us; speedup vs baseline: 1.0064x; 1.0064x over previous
//
#include <hip/hip_runtime.h>

// Problem constants
#define BB 256
#define NN 5
#define CHW 64000            // C*H*W floats per (b,n)
#define DD 800               // 32*5*5 pooled dims
#define EPSF 1e-8f

#define NBLOCKS 128          // concurrent-b footprint = 128 * 1.28 MB = 164 MB < 256 MB L3
#define TPB 1024

typedef float f4 __attribute__((ext_vector_type(4)));

// Fused persistent kernel: each block owns one b at a time.
//  Phase A: pool x[b] -> feats LDS (exact block mean, float2 = one (h,ow) pair)
//  Phase B: wave 0 computes cosine sims (proxy = sum_n feats[n]) -> s_sim LDS
//  Phase C: out[b] = sum_n sim[n] * x[b,n]  (re-read hits L3; nontemporal store)
__global__ __launch_bounds__(TPB) void k_fused(const float* __restrict__ x,
                                               float* __restrict__ out) {
    __shared__ float feats[NN][DD];   // 16 KB
    __shared__ float s_sim[NN];
    const int tid = threadIdx.x;

    for (int b = blockIdx.x; b < BB; b += gridDim.x) {
        const float* __restrict__ xb = x + (size_t)b * NN * CHW;

        // ---------------- Phase A: pool ----------------
        for (int idx = tid; idx < NN * DD; idx += TPB) {
            const int n = idx / DD;
            const int d = idx - n * DD;
            const int oc  = d / 25;
            const int rem = d - oc * 25;
            const int oh  = rem / 5;
            const int ow  = rem - oh * 5;
            const float2* __restrict__ xp =
                reinterpret_cast<const float2*>(xb + (size_t)n * CHW);
            // float2 index: c*50 + h*5 + ow, with c = oc*20+cc, h = oh*2+{0,1}
            const int base = oc * 20 * 50 + oh * 10 + ow;
            float s = 0.f;
            #pragma unroll
            for (int cc = 0; cc < 20; ++cc) {
                float2 a = xp[base + cc * 50];
                float2 c = xp[base + cc * 50 + 5];
                s += (a.x + a.y) + (c.x + c.y);
            }
            feats[n][d] = s * (1.0f / 80.0f);
        }
        __syncthreads();

        // ---------------- Phase B: sims (wave 0 only) ----------------
        if (tid < 64) {
            float dot[NN] = {0.f, 0.f, 0.f, 0.f, 0.f};
            float na2[NN] = {0.f, 0.f, 0.f, 0.f, 0.f};
            float nb2 = 0.f;
            for (int d = tid; d < DD; d += 64) {
                float f[NN];
                float p = 0.f;
                #pragma unroll
                for (int n = 0; n < NN; ++n) { f[n] = feats[n][d]; p += f[n]; }
                #pragma unroll
                for (int n = 0; n < NN; ++n) {
                    dot[n] += f[n] * p;
                    na2[n] += f[n] * f[n];
                }
                nb2 += p * p;
            }
            #pragma unroll
            for (int off = 32; off >= 1; off >>= 1) {
                #pragma unroll
                for (int n = 0; n < NN; ++n) {
                    dot[n] += __shfl_down(dot[n], off, 64);
                    na2[n] += __shfl_down(na2[n], off, 64);
                }
                nb2 += __shfl_down(nb2, off, 64);
            }
            if (tid == 0) {
                const float nb = sqrtf(nb2);
                #pragma unroll
                for (int n = 0; n < NN; ++n) {
                    const float denom = fmaxf(sqrtf(na2[n]) * nb, EPSF);
                    s_sim[n] = dot[n] / denom;
                }
            }
        }
        __syncthreads();

        // ---------------- Phase C: weighted sum ----------------
        const float s0 = s_sim[0];
        const float s1 = s_sim[1];
        const float s2 = s_sim[2];
        const float s3 = s_sim[3];
        const float s4 = s_sim[4];
        const f4* __restrict__ xp4 = reinterpret_cast<const f4*>(xb);
        f4* __restrict__ op4 = reinterpret_cast<f4*>(out + (size_t)b * CHW);
        for (int i = tid; i < CHW / 4; i += TPB) {
            f4 o = s0 * xp4[i]
                 + s1 * xp4[i + 1 * (CHW / 4)]
                 + s2 * xp4[i + 2 * (CHW / 4)]
                 + s3 * xp4[i + 3 * (CHW / 4)]
                 + s4 * xp4[i + 4 * (CHW / 4)];
            __builtin_nontemporal_store(o, op4 + i);
        }
        // No barrier needed here: next Phase A writes feats only after the
        // post-A barrier; s_sim is re-written only after that barrier too.
        __syncthreads();
    }
}

extern "C" void kernel_launch(void* const* d_in, const int* in_sizes, int n_in,
                              void* d_out, int out_size, void* d_ws, size_t ws_size,
                              hipStream_t stream) {
    const float* x = (const float*)d_in[0];
    float* out = (float*)d_out;
    k_fused<<<NBLOCKS, TPB, 0, stream>>>(x, out);
}

// Round 3
// 129.106 us; speedup vs baseline: 1.1046x; 1.0976x over previous
//
#include <hip/hip_runtime.h>

// Problem constants
#define BB 256
#define NN 5
#define CHW 64000            // C*H*W floats per (b,n)
#define DD 800               // 32*5*5 pooled dims
#define EPSF 1e-8f
#define TPB 1024

typedef float f4 __attribute__((ext_vector_type(4)));

// Fused kernel, one b per block (grid = 256):
//  Phase A: pool x[b] -> feats LDS. Thread t<800 owns (n,oc,oh), computes the
//           5 ow cells from 5 float4 per channel (rows 2oh,2oh+1 = 20 floats).
//  Phase B: all 16 waves: one d per thread, two-level reduce -> sims.
//  Phase C: out[b] = sum_n sim[n]*x[b,n]; re-read of x[b] hits L3.
__global__ __launch_bounds__(TPB, 4) void k_fused(const float* __restrict__ x,
                                                  float* __restrict__ out) {
    __shared__ float feats[NN * DD];   // 16000 B
    __shared__ float red[17][11];      // 16 wave partials + 1 final row
    __shared__ float s_sim[NN];
    const int tid = threadIdx.x;
    const int b = blockIdx.x;
    const float* __restrict__ xb = x + (size_t)b * NN * CHW;

    // ---------------- Phase A: pool ----------------
    if (tid < NN * 160) {
        const int n  = tid / 160;
        const int r  = tid - n * 160;
        const int oc = r / 5;
        const int oh = r - oc * 5;
        // channel c = oc*20+cc; rows h=2oh,2oh+1 are 20 contiguous floats.
        const f4* __restrict__ p = reinterpret_cast<const f4*>(xb) +
                                   (size_t)n * (CHW / 4) + oc * 500 + oh * 5;
        float s0 = 0.f, s1 = 0.f, s2 = 0.f, s3 = 0.f, s4 = 0.f;
        #pragma unroll 4
        for (int cc = 0; cc < 20; ++cc) {
            const f4 v0 = p[cc * 25 + 0];   // h0 w0..3
            const f4 v1 = p[cc * 25 + 1];   // h0 w4..7
            const f4 v2 = p[cc * 25 + 2];   // h0 w8,9 | h1 w0,1
            const f4 v3 = p[cc * 25 + 3];   // h1 w2..5
            const f4 v4 = p[cc * 25 + 4];   // h1 w6..9
            s0 += (v0.x + v0.y) + (v2.z + v2.w);
            s1 += (v0.z + v0.w) + (v3.x + v3.y);
            s2 += (v1.x + v1.y) + (v3.z + v3.w);
            s3 += (v1.z + v1.w) + (v4.x + v4.y);
            s4 += (v2.x + v2.y) + (v4.z + v4.w);
        }
        float* fp = feats + n * DD + oc * 25 + oh * 5;
        fp[0] = s0 * (1.f / 80.f);
        fp[1] = s1 * (1.f / 80.f);
        fp[2] = s2 * (1.f / 80.f);
        fp[3] = s3 * (1.f / 80.f);
        fp[4] = s4 * (1.f / 80.f);
    }
    __syncthreads();

    // ---------------- Phase B: sims, all waves ----------------
    float dot[NN] = {0.f, 0.f, 0.f, 0.f, 0.f};
    float na2[NN] = {0.f, 0.f, 0.f, 0.f, 0.f};
    float nb2 = 0.f;
    if (tid < DD) {
        float f[NN];
        float pr = 0.f;
        #pragma unroll
        for (int n = 0; n < NN; ++n) { f[n] = feats[n * DD + tid]; pr += f[n]; }
        #pragma unroll
        for (int n = 0; n < NN; ++n) { dot[n] = f[n] * pr; na2[n] = f[n] * f[n]; }
        nb2 = pr * pr;
    }
    #pragma unroll
    for (int off = 32; off >= 1; off >>= 1) {
        #pragma unroll
        for (int n = 0; n < NN; ++n) {
            dot[n] += __shfl_down(dot[n], off, 64);
            na2[n] += __shfl_down(na2[n], off, 64);
        }
        nb2 += __shfl_down(nb2, off, 64);
    }
    const int wv = tid >> 6;
    if ((tid & 63) == 0) {
        #pragma unroll
        for (int n = 0; n < NN; ++n) { red[wv][n] = dot[n]; red[wv][5 + n] = na2[n]; }
        red[wv][10] = nb2;
    }
    __syncthreads();
    if (tid < 11) {
        float s = 0.f;
        #pragma unroll
        for (int w = 0; w < 16; ++w) s += red[w][tid];
        red[16][tid] = s;
    }
    __syncthreads();
    if (tid == 0) {
        const float nb = sqrtf(red[16][10]);
        #pragma unroll
        for (int n = 0; n < NN; ++n) {
            const float denom = fmaxf(sqrtf(red[16][5 + n]) * nb, EPSF);
            s_sim[n] = red[16][n] / denom;
        }
    }
    __syncthreads();

    // ---------------- Phase C: weighted sum ----------------
    const float w0 = s_sim[0];
    const float w1 = s_sim[1];
    const float w2 = s_sim[2];
    const float w3 = s_sim[3];
    const float w4 = s_sim[4];
    const f4* __restrict__ xp4 = reinterpret_cast<const f4*>(xb);
    f4* __restrict__ op4 = reinterpret_cast<f4*>(out + (size_t)b * CHW);
    #pragma unroll 2
    for (int i = tid; i < CHW / 4; i += TPB) {
        f4 o = w0 * xp4[i]
             + w1 * xp4[i + 1 * (CHW / 4)]
             + w2 * xp4[i + 2 * (CHW / 4)]
             + w3 * xp4[i + 3 * (CHW / 4)]
             + w4 * xp4[i + 4 * (CHW / 4)];
        __builtin_nontemporal_store(o, op4 + i);
    }
}

extern "C" void kernel_launch(void* const* d_in, const int* in_sizes, int n_in,
                              void* d_out, int out_size, void* d_ws, size_t ws_size,
                              hipStream_t stream) {
    const float* x = (const float*)d_in[0];
    float* out = (float*)d_out;
    k_fused<<<BB, TPB, 0, stream>>>(x, out);
}